// Round 5
// baseline (289.532 us; speedup 1.0000x reference)
//
#include <hip/hip_runtime.h>

#define CROP 81
#define NB   64
#define IMH  512
#define IMW  512
#define PIX  (CROP * CROP)
#define IMG_OUT_ELEMS (NB * 6 * 3 * PIX)   // 7,558,272

// 3 rows per thread: 81 = 3*27. Thread space: N*6*27*81
#define RBLK   3
#define NROWT  27
#define TOTAL3 (NB * 6 * NROWT * CROP)     // 839,808

__global__ __launch_bounds__(256) void selectnet_kernel(
    const float* __restrict__ img,     // (64,3,512,512)
    const int*   __restrict__ label,   // (64,512,512)
    const float* __restrict__ points,  // (64,9,2)
    float* __restrict__ out)           // [croped_image | croped_pred]
{
    int idx = blockIdx.x * 256 + threadIdx.x;
    if (idx >= TOTAL3) return;

    int j  = idx % CROP;
    int t  = idx / CROP;
    int ib = t % NROWT;
    t /= NROWT;
    int k = t % 6;
    int n = t / 6;

    // ---- pts6[n,k] = points[n,k+1] for k<5, else mean(points[n,6:9]) ----
    const float* pn = points + n * 18;   // (9,2): [...,0]=py, [...,1]=px
    float py, px;
    if (k < 5) {
        py = pn[(k + 1) * 2 + 0];
        px = pn[(k + 1) * 2 + 1];
    } else {
        py = __fdiv_rn(__fadd_rn(__fadd_rn(pn[12], pn[14]), pn[16]), 3.0f);
        px = __fdiv_rn(__fadd_rn(__fadd_rn(pn[13], pn[15]), pn[17]), 3.0f);
    }

    // ======== x-chain: depends only on (n,k,j) — computed ONCE ========
    const float sx = (float)(80.0 / 511.0);
    float basej = (float)((double)j * 0.025 - 1.0);
    float tx = __fadd_rn(-1.0f, __fdiv_rn(__fmul_rn(2.0f, px), 511.0f));
    float gx = __fadd_rn(__fmul_rn(sx, basej), tx);
    float ix = __fmul_rn(__fmul_rn(__fadd_rn(gx, 1.0f), 0.5f), 511.0f);

    float x0f = floorf(ix);
    float x1f = x0f + 1.0f;
    float wx1 = ix - x0f, wx0 = 1.0f - wx1;
    float vx0 = (x0f >= 0.0f && x0f <= 511.0f) ? 1.0f : 0.0f;
    float vx1 = (x1f >= 0.0f && x1f <= 511.0f) ? 1.0f : 0.0f;
    int xi0 = (int)fminf(fmaxf(x0f, 0.0f), 511.0f);
    int xi1 = (int)fminf(fmaxf(x1f, 0.0f), 511.0f);
    float xr  = rintf(ix);                 // half-to-even == np.round
    float nvx = (xr >= 0.0f && xr <= 511.0f) ? 1.0f : 0.0f;
    int   xn  = (int)fminf(fmaxf(xr, 0.0f), 511.0f);

    const float ty = __fadd_rn(-1.0f, __fdiv_rn(__fmul_rn(2.0f, py), 511.0f));
    const float sy = 0.15625f;             // 80/512 exact

    const size_t img_n   = (size_t)n * 3 * IMH * IMW;
    const size_t lab_n   = (size_t)n * IMH * IMW;
    const size_t out_img = ((size_t)(n * 6 + k) * 3) * PIX;
    const size_t out_prd = (size_t)IMG_OUT_ELEMS + (size_t)(n * 6 + k) * PIX;

    #pragma unroll
    for (int r = 0; r < RBLK; ++r) {
        int i = ib * RBLK + r;

        // ---- y-chain (exact reference f32 op order) ----
        float basei = (float)((double)i * 0.025 - 1.0);
        float gy = __fadd_rn(__fmul_rn(sy, basei), ty);
        float iy = __fmul_rn(__fmul_rn(__fadd_rn(gy, 1.0f), 0.5f), 511.0f);

        float y0f = floorf(iy);
        float y1f = y0f + 1.0f;
        float wy1 = iy - y0f, wy0 = 1.0f - wy1;
        float vy0 = (y0f >= 0.0f && y0f <= 511.0f) ? 1.0f : 0.0f;
        float vy1 = (y1f >= 0.0f && y1f <= 511.0f) ? 1.0f : 0.0f;
        int r0 = ((int)fminf(fmaxf(y0f, 0.0f), 511.0f)) * IMW;
        int r1 = ((int)fminf(fmaxf(y1f, 0.0f), 511.0f)) * IMW;

        float v00 = vx0 * vy0, v10 = vx1 * vy0, v01 = vx0 * vy1, v11 = vx1 * vy1;
        float w00 = wx0 * wy0, w10 = wx1 * wy0, w01 = wx0 * wy1, w11 = wx1 * wy1;

        size_t ob = out_img + (size_t)i * CROP + j;
        #pragma unroll
        for (int c = 0; c < 3; ++c) {
            const float* ic = img + img_n + (size_t)c * (IMH * IMW);
            float g00 = ic[r0 + xi0] * v00;
            float g10 = ic[r0 + xi1] * v10;
            float g01 = ic[r1 + xi0] * v01;
            float g11 = ic[r1 + xi1] * v11;
            float val = ((g00 * w00 + g10 * w10) + g01 * w01) + g11 * w11;
            out[ob + (size_t)c * PIX] = val;
        }

        // ---- nearest label + class transform ----
        float yr  = rintf(iy);
        float nvy = (yr >= 0.0f && yr <= 511.0f) ? 1.0f : 0.0f;
        int   rn  = ((int)fminf(fmaxf(yr, 0.0f), 511.0f)) * IMW;
        int lab = label[lab_n + rn + xn];
        float labv = (nvx * nvy != 0.0f) ? (float)lab : 0.0f;

        float pred;
        if (k < 5) {
            pred = (labv == (float)(k + 1)) ? 1.0f : 0.0f;
        } else {
            pred = (labv == 6.0f) ? 1.0f
                 : (labv == 7.0f) ? 2.0f
                 : (labv == 8.0f) ? 3.0f
                 : 0.0f;
        }
        out[out_prd + (size_t)i * CROP + j] = pred;
    }
}

extern "C" void kernel_launch(void* const* d_in, const int* in_sizes, int n_in,
                              void* d_out, int out_size, void* d_ws, size_t ws_size,
                              hipStream_t stream) {
    const float* img    = (const float*)d_in[0];
    const int*   label  = (const int*)d_in[1];
    const float* points = (const float*)d_in[2];
    float* out = (float*)d_out;

    int blocks = (TOTAL3 + 255) / 256;
    selectnet_kernel<<<blocks, 256, 0, stream>>>(img, label, points, out);
}